// Round 5
// baseline (307.425 us; speedup 1.0000x reference)
//
#include <hip/hip_runtime.h>
#include <math.h>

#define BB 4
#define LL 2048
#define DD 1024
#define HH 16
#define HD 64
#define BL (BB*LL)

typedef __attribute__((ext_vector_type(8))) short bf16x8;
typedef __attribute__((ext_vector_type(4))) short bf16x4;
typedef __attribute__((ext_vector_type(4))) float f32x4;

__device__ inline short f2bf(float f) {
    union { float f; unsigned u; } v; v.f = f;
    unsigned r = v.u + 0x7fffu + ((v.u >> 16) & 1u);   // RNE
    return (short)(r >> 16);
}

// pack two fp32 -> two bf16 (truncation; p>=0 so bias is benign, ~2^-9 rel)
// single v_perm_b32: D = {b.b3, b.b2, a.b3, a.b2}
__device__ inline unsigned pk_bf16(float a, float b) {
    union { float f; unsigned u; } x, y; x.f = a; y.f = b;
#if __has_builtin(__builtin_amdgcn_perm)
    return __builtin_amdgcn_perm(y.u, x.u, 0x07060302u);
#else
    return (x.u >> 16) | (y.u & 0xffff0000u);
#endif
}

__device__ inline float exp2x(float x) {
#if __has_builtin(__builtin_amdgcn_exp2f)
    return __builtin_amdgcn_exp2f(x);
#else
    return exp2f(x);
#endif
}

__device__ inline void gload_lds16(const void* g, void* l) {
    __builtin_amdgcn_global_load_lds(
        (const __attribute__((address_space(1))) unsigned int*)g,
        (__attribute__((address_space(3))) unsigned int*)l, 16, 0, 0);
}

// ---------------------------------------------------------------------------
// fp32 -> bf16 cast, 8 elem/thread.
// ---------------------------------------------------------------------------
__global__ __launch_bounds__(256) void cast_kernel(
    const float* __restrict__ in, short* __restrict__ out, int n)
{
    int i = (blockIdx.x * 256 + threadIdx.x) * 8;
    float4 a = *(const float4*)(in + i);
    float4 b = *(const float4*)(in + i + 4);
    bf16x8 o;
    o[0]=f2bf(a.x); o[1]=f2bf(a.y); o[2]=f2bf(a.z); o[3]=f2bf(a.w);
    o[4]=f2bf(b.x); o[5]=f2bf(b.y); o[6]=f2bf(b.z); o[7]=f2bf(b.w);
    *(bf16x8*)(out + i) = o;
}

// 4 weight matrices (contiguous dsts), one launch. grid = 4 * n_w/2048.
__global__ __launch_bounds__(256) void cast4_kernel(
    const float* __restrict__ w0, const float* __restrict__ w1,
    const float* __restrict__ w2, const float* __restrict__ w3,
    short* __restrict__ out)
{
    const int nw_blocks = (DD*DD) / 2048;
    int sel = blockIdx.x / nw_blocks;
    int blk = blockIdx.x % nw_blocks;
    const float* in = (sel == 0) ? w0 : (sel == 1) ? w1 : (sel == 2) ? w2 : w3;
    int i = (blk * 256 + threadIdx.x) * 8;
    float4 a = *(const float4*)(in + i);
    float4 b = *(const float4*)(in + i + 4);
    bf16x8 o;
    o[0]=f2bf(a.x); o[1]=f2bf(a.y); o[2]=f2bf(a.z); o[3]=f2bf(a.w);
    o[4]=f2bf(b.x); o[5]=f2bf(b.y); o[6]=f2bf(b.z); o[7]=f2bf(b.w);
    *(bf16x8*)(out + (size_t)sel * DD * DD + i) = o;
}

// ---------------------------------------------------------------------------
// RoPE table: tab[l*32 + f] = (cos, sin) of l * 10000^(-f/32), f=0..31.
// ---------------------------------------------------------------------------
__global__ __launch_bounds__(256) void rope_tab_kernel(float2* __restrict__ tab)
{
    int idx = blockIdx.x * 256 + threadIdx.x;
    int lq = idx >> 5, f = idx & 31;
    float inv = __expf((float)f * (-9.210340371976184f / 32.0f));
    float s, c;
    sincosf((float)lq * inv, &s, &c);
    tab[idx] = make_float2(c, s);
}

// ---------------------------------------------------------------------------
// Shared 128x128-tile bf16 MFMA K-loop (m97 2-barrier structure, 32 KB LDS —
// R10's 64KB dbuf reverted: it cost a residency slot, occupancy 19.6->11%).
// R11: XOR-swizzled LDS columns (rule #21: linear gload_lds dest +
// pre-swizzled GLOBAL source + swizzled read). Old layout had row stride
// exactly 128 B -> frag reads stacked 16 lanes on one bank quad using only
// half the banks (1.9e7 conflict cycles). Swizzle: LDS[row][col] holds
// global col (col ^ (row&7)); reads XOR 8*(ln&7) -> all 8 bank quads
// covered evenly, conflict-free. Global coalescing unchanged (permutation
// within each 128-B row).
// ---------------------------------------------------------------------------
__device__ inline void gemm_bt_128(const short* __restrict__ A,
                                   const short* __restrict__ B,
                                   short* Ash, short* Bsh,
                                   int i0, int n0, f32x4 (&acc)[4][4])
{
    const int t  = threadIdx.x;
    const int w  = t >> 6;
    const int l  = t & 63;
    const int g  = (t >> 4) & 3;
    const int ln = t & 15;
    const int rh = (w >> 1) * 64;
    const int ch = (w & 1) * 64;
    const int srow = w * 8 + (l >> 3);
    const int skol = ((l & 7) ^ (l >> 3)) * 8;   // source col swizzled by row&7
    const int rsw  = 8 * (ln & 7);               // read-side XOR key (row&7 == ln&7)

    for (int k0 = 0; k0 < DD; k0 += 64) {
        __syncthreads();
        const short* ga = A + (size_t)(i0 + srow) * DD + k0 + skol;
        const short* gb = B + (size_t)(n0 + srow) * DD + k0 + skol;
        short* la = Ash + w * 512;   // wave-uniform base
        short* lb = Bsh + w * 512;
        #pragma unroll
        for (int j = 0; j < 4; ++j) {
            gload_lds16(ga + j * 32 * DD, la + j * 2048);
            gload_lds16(gb + j * 32 * DD, lb + j * 2048);
        }
        __syncthreads();

        #pragma unroll
        for (int kk = 0; kk < 2; ++kk) {
            bf16x8 af[4], bfr[4];
            #pragma unroll
            for (int mi = 0; mi < 4; ++mi)
                af[mi] = *(const bf16x8*)(Ash + (rh + mi*16 + ln)*64 + ((kk*32 + 8*g) ^ rsw));
            #pragma unroll
            for (int nj = 0; nj < 4; ++nj)
                bfr[nj] = *(const bf16x8*)(Bsh + (ch + nj*16 + ln)*64 + ((kk*32 + 8*g) ^ rsw));
            #pragma unroll
            for (int mi = 0; mi < 4; ++mi)
                #pragma unroll
                for (int nj = 0; nj < 4; ++nj)
                    acc[mi][nj] = __builtin_amdgcn_mfma_f32_16x16x32_bf16(
                        af[mi], bfr[nj], acc[mi][nj], 0, 0, 0);
        }
    }
}

// ---------------------------------------------------------------------------
// Kernel 1: QKV projection + RoPE. 1-D grid 1536, XCD-aware decode:
// xcd r = gid&7 owns i-tiles r*8..r*8+7 (2 MB of x stays in that XCD's L2)
// and iterates all 24 (n,z) W-tiles (W-tile reused back-to-back).
// z=0/1: Q/K roped via table, Q scaled 0.125*log2(e), layout (B,H,L,Hd).
// z=2: V transposed (B,H,Hd,L) via two-pass LDS transpose. V keys are
// bit-permuted within each 64-key tile (key' [5:4]=g,[3]=hb,[2]=a,[1:0]=r
// of key = 32hb+16a+4g+r) so attn's PV B-frags are single b128 LDS reads.
// ---------------------------------------------------------------------------
__global__ __launch_bounds__(256) void qkv_mfma_kernel(
    const short* __restrict__ xb, const short* __restrict__ Wqb,
    const short* __restrict__ Wkb, const short* __restrict__ Wvb,
    const float2* __restrict__ rope_tab,
    short* __restrict__ Qo, short* __restrict__ Ko, short* __restrict__ Vo)
{
    __shared__ short Ash[128*64];
    __shared__ short Bsh[128*64];

    const int gid = blockIdx.x;
    const int r8  = gid & 7;           // XCD slot (round-robin heuristic)
    const int u   = gid >> 3;          // 0..191
    const int i_idx = r8 * 8 + (u & 7);      // 0..63
    const int nz  = u >> 3;                  // 0..23
    const int n_idx = nz & 7;                // 0..7
    const int z   = nz >> 3;                 // 0..2

    const short* Wm = (z == 0) ? Wqb : ((z == 1) ? Wkb : Wvb);
    const int i0 = i_idx * 128;
    const int n0 = n_idx * 128;

    f32x4 acc[4][4];
    #pragma unroll
    for (int mi = 0; mi < 4; ++mi)
        #pragma unroll
        for (int nj = 0; nj < 4; ++nj) acc[mi][nj] = (f32x4){0.f,0.f,0.f,0.f};

    gemm_bt_128(xb, Wm, Ash, Bsh, i0, n0, acc);

    const int t  = threadIdx.x;
    const int w  = t >> 6;
    const int g  = (t >> 4) & 3;
    const int ln = t & 15;
    const int rh = (w >> 1) * 64;

    if (z == 2) {
        // two passes over heads; buf[64 d][136 seq-stride] spans Ash..Bsh.
        short* buf = Ash;
        const int b = i0 >> 11, l0 = i0 & (LL - 1);
        const int d = t >> 2;
        const int c = t & 3;
        #pragma unroll
        for (int hp = 0; hp < 2; ++hp) {
            __syncthreads();
            if ((w & 1) == hp) {
                #pragma unroll
                for (int nj = 0; nj < 4; ++nj)
                    #pragma unroll
                    for (int mi = 0; mi < 4; ++mi)
                        #pragma unroll
                        for (int r = 0; r < 4; ++r)
                            buf[(nj*16 + ln)*136 + rh + mi*16 + 4*g + r]
                                = f2bf(acc[mi][nj][r]);
            }
            __syncthreads();
            short* dst = Vo + ((size_t)((b*HH + n_idx*2 + hp)*HD + d)) * LL + l0;
            // permuted store: global key base = 8c + 32j (within 128-row l0);
            // tile tb = 64*(j>>1), hb = j&1, a = c>>1, g0 = 2*(c&1);
            // keys k0..k0+3 -> key' 16*g0+8*hb+4*a..+3 ; k0+4..k0+7 -> g0+1.
            #pragma unroll
            for (int j = 0; j < 4; ++j) {
                const short* src = buf + d*136 + c*8 + j*32;
                bf16x4 lo = *(const bf16x4*)(src);
                bf16x4 hi = *(const bf16x4*)(src + 4);
                const int tb = (j >> 1) * 64;
                const int hb = j & 1;
                const int aa = c >> 1;
                const int g0 = (c & 1) * 2;
                *(bf16x4*)(dst + tb + g0*16       + hb*8 + aa*4) = lo;
                *(bf16x4*)(dst + tb + (g0+1)*16   + hb*8 + aa*4) = hi;
            }
        }
    } else {
        const int h = n_idx * 2 + (w & 1);
        short* Om = (z == 0) ? Qo : Ko;
        // Q: 1/sqrt(64) * log2(e) so scores feed exp2 directly
        const float sc = (z == 0) ? 0.180336880111112f : 1.0f;
        #pragma unroll
        for (int mi = 0; mi < 4; ++mi)
            #pragma unroll
            for (int r = 0; r < 4; ++r) {
                int i = i0 + rh + mi*16 + 4*g + r;
                int b = i >> 11, lq = i & (LL - 1);
                float2 cs0 = rope_tab[lq*32 + ln];        // freq ln
                float2 cs1 = rope_tab[lq*32 + ln + 16];   // freq ln+16
                float r0 = (acc[mi][0][r]*cs0.x - acc[mi][2][r]*cs0.y) * sc;
                float r2 = (acc[mi][2][r]*cs0.x + acc[mi][0][r]*cs0.y) * sc;
                float r1 = (acc[mi][1][r]*cs1.x - acc[mi][3][r]*cs1.y) * sc;
                float r3 = (acc[mi][3][r]*cs1.x + acc[mi][1][r]*cs1.y) * sc;
                size_t base = ((size_t)(b*HH + h) * LL + lq) * HD;
                Om[base + ln     ] = f2bf(r0);
                Om[base + ln + 16] = f2bf(r1);
                Om[base + ln + 32] = f2bf(r2);
                Om[base + ln + 48] = f2bf(r3);
            }
    }
}

// ---------------------------------------------------------------------------
// Kernel 2: bf16 MFMA flash attention (unchanged from R9).
// grid = (B*H, L/128): bh on x => the 16 q-tile blocks sharing one bh get
// gid == bh (mod 8) -> same XCD -> K/V stay in one L2.
//  (a) l-sum via MFMA ones-trick (lsum element r == O row 4g+r).
//  (b) VT global layout key-bit-permuted -> PV B-frag = one b128 LDS read.
//  (c) pk_bf16 = single v_perm_b32.
// ---------------------------------------------------------------------------
__global__ __launch_bounds__(256) void attn_kernel(
    const short* __restrict__ Q, const short* __restrict__ K,
    const short* __restrict__ VT, short* __restrict__ AO)
{
    __shared__ short Ksh[64*72];   // [key][d]
    __shared__ short VTs[64*72];   // [d][key']  (key' = permuted key)

    const int t  = threadIdx.x;
    const int w  = t >> 6;
    const int l  = t & 63;
    const int g  = l >> 4;
    const int ln = l & 15;

    const int bh = blockIdx.x;
    const int q0 = blockIdx.y * 128;
    const short* Qb  = Q  + ((size_t)bh * LL + q0 + w*32) * HD;
    const short* Kb  = K  + (size_t)bh * LL * HD;
    const short* VTb = VT + (size_t)bh * HD * LL;

    // Q B-frags: [n=q=ln][k=d=8g+j(+32)]
    bf16x8 qb[2][2];
    #pragma unroll
    for (int qi = 0; qi < 2; ++qi) {
        qb[qi][0] = *(const bf16x8*)(Qb + (size_t)(qi*16 + ln)*HD + 8*g);
        qb[qi][1] = *(const bf16x8*)(Qb + (size_t)(qi*16 + ln)*HD + 32 + 8*g);
    }

    const bf16x8 ONES = { (short)0x3F80, (short)0x3F80, (short)0x3F80, (short)0x3F80,
                          (short)0x3F80, (short)0x3F80, (short)0x3F80, (short)0x3F80 };

    f32x4 O[2][4];                 // O[qi][db]: row q=4g+r, col d=db*16+ln
    #pragma unroll
    for (int qi = 0; qi < 2; ++qi)
        #pragma unroll
        for (int db = 0; db < 4; ++db) O[qi][db] = (f32x4){0.f,0.f,0.f,0.f};
    f32x4 lsum[2];                 // lsum[qi][r] = l for row q=4g+r (any ln)
    lsum[0] = (f32x4){0.f,0.f,0.f,0.f};
    lsum[1] = (f32x4){0.f,0.f,0.f,0.f};

    const int sr = t >> 2;          // staging row (key for Ksh, d for VTs)
    const int sc = (t & 3) << 4;    // staging col chunk

    for (int kt = 0; kt < LL; kt += 64) {
        bf16x8 k0 = *(const bf16x8*)(Kb  + (size_t)(kt + sr)*HD + sc);
        bf16x8 k1 = *(const bf16x8*)(Kb  + (size_t)(kt + sr)*HD + sc + 8);
        bf16x8 v0 = *(const bf16x8*)(VTb + (size_t)sr*LL + kt + sc);
        bf16x8 v1 = *(const bf16x8*)(VTb + (size_t)sr*LL + kt + sc + 8);
        __syncthreads();           // previous tile fully consumed
        *(bf16x8*)(Ksh + sr*72 + sc)     = k0;
        *(bf16x8*)(Ksh + sr*72 + sc + 8) = k1;
        *(bf16x8*)(VTs + sr*72 + sc)     = v0;
        *(bf16x8*)(VTs + sr*72 + sc + 8) = v1;
        __syncthreads();

        unsigned pf[2][4][2];      // [qi][kb]: keys (4g,4g+1),(4g+2,4g+3)
        #pragma unroll
        for (int kb = 0; kb < 4; ++kb) {
            // K A-frags: [m=key=kb*16+ln][k=d]
            bf16x8 ka0 = *(const bf16x8*)(Ksh + (kb*16 + ln)*72 + 8*g);
            bf16x8 ka1 = *(const bf16x8*)(Ksh + (kb*16 + ln)*72 + 32 + 8*g);
            #pragma unroll
            for (int qi = 0; qi < 2; ++qi) {
                f32x4 S = (f32x4){0.f,0.f,0.f,0.f};
                S = __builtin_amdgcn_mfma_f32_16x16x32_bf16(ka0, qb[qi][0], S, 0, 0, 0);
                S = __builtin_amdgcn_mfma_f32_16x16x32_bf16(ka1, qb[qi][1], S, 0, 0, 0);
                float p0 = exp2x(S[0]), p1 = exp2x(S[1]);
                float p2 = exp2x(S[2]), p3 = exp2x(S[3]);
                pf[qi][kb][0] = pk_bf16(p0, p1);
                pf[qi][kb][1] = pk_bf16(p2, p3);
            }
        }

        // P A-frags for PV/lsum: slot (g,j) <-> key 32hb + 16*(j>>2) + 4g + (j&3)
        bf16x8 pa[2][2];
        #pragma unroll
        for (int qi = 0; qi < 2; ++qi)
            #pragma unroll
            for (int hb = 0; hb < 2; ++hb) {
                union { unsigned u[4]; bf16x8 v; } a;
                a.u[0] = pf[qi][2*hb][0];   a.u[1] = pf[qi][2*hb][1];
                a.u[2] = pf[qi][2*hb+1][0]; a.u[3] = pf[qi][2*hb+1][1];
                pa[qi][hb] = a.v;
            }

        // l-sum: one MFMA per (hb,qi) with all-ones B
        #pragma unroll
        for (int hb = 0; hb < 2; ++hb) {
            lsum[0] = __builtin_amdgcn_mfma_f32_16x16x32_bf16(pa[0][hb], ONES, lsum[0], 0, 0, 0);
            lsum[1] = __builtin_amdgcn_mfma_f32_16x16x32_bf16(pa[1][hb], ONES, lsum[1], 0, 0, 0);
        }

        // PV via 16x16x32: B-frag = one b128 from permuted VTs
        #pragma unroll
        for (int hb = 0; hb < 2; ++hb) {
            #pragma unroll
            for (int db = 0; db < 4; ++db) {
                bf16x8 vf = *(const bf16x8*)(VTs + (db*16 + ln)*72 + 16*g + 8*hb);
                O[0][db] = __builtin_amdgcn_mfma_f32_16x16x32_bf16(pa[0][hb], vf, O[0][db], 0, 0, 0);
                O[1][db] = __builtin_amdgcn_mfma_f32_16x16x32_bf16(pa[1][hb], vf, O[1][db], 0, 0, 0);
            }
        }
    }

    // epilogue: lsum[qi][r] is exactly l for row q=4g+r — no shuffles.
    const int b = bh >> 4, h = bh & 15;
    #pragma unroll
    for (int qi = 0; qi < 2; ++qi) {
        #pragma unroll
        for (int r = 0; r < 4; ++r) {
            float inv = 1.0f / lsum[qi][r];
            int q = q0 + w*32 + qi*16 + 4*g + r;
            size_t base = ((size_t)(b*LL + q)) * DD + h*HD;
            #pragma unroll
            for (int db = 0; db < 4; ++db)
                AO[base + db*16 + ln] = f2bf(O[qi][db][r] * inv);
        }
    }
}

// ---------------------------------------------------------------------------
// Kernel 3: output projection. 1-D grid 512, same XCD-aware decode as qkv:
// each XCD owns 8 i-tiles of A + iterates the 8 Wo n-tiles.
// ---------------------------------------------------------------------------
__global__ __launch_bounds__(256) void oproj_mfma_kernel(
    const short* __restrict__ A, const short* __restrict__ Wob,
    float* __restrict__ out)
{
    __shared__ short Ash[128*64];
    __shared__ short Bsh[128*64];

    const int gid = blockIdx.x;
    const int r8  = gid & 7;
    const int u   = gid >> 3;              // 0..63
    const int i_idx = r8 * 8 + (u & 7);    // 0..63
    const int n_idx = u >> 3;              // 0..7
    const int i0 = i_idx * 128;
    const int n0 = n_idx * 128;

    f32x4 acc[4][4];
    #pragma unroll
    for (int mi = 0; mi < 4; ++mi)
        #pragma unroll
        for (int nj = 0; nj < 4; ++nj) acc[mi][nj] = (f32x4){0.f,0.f,0.f,0.f};

    gemm_bt_128(A, Wob, Ash, Bsh, i0, n0, acc);

    const int t  = threadIdx.x;
    const int w  = t >> 6;
    const int g  = (t >> 4) & 3;
    const int ln = t & 15;
    const int rh = (w >> 1) * 64;
    const int ch = (w & 1) * 64;

    #pragma unroll
    for (int mi = 0; mi < 4; ++mi)
        #pragma unroll
        for (int r = 0; r < 4; ++r) {
            size_t base = (size_t)(i0 + rh + mi*16 + 4*g + r) * DD + n0 + ch;
            #pragma unroll
            for (int nj = 0; nj < 4; ++nj)
                out[base + nj*16 + ln] = acc[mi][nj][r];
        }
}

// ---------------------------------------------------------------------------
extern "C" void kernel_launch(void* const* d_in, const int* in_sizes, int n_in,
                              void* d_out, int out_size, void* d_ws, size_t ws_size,
                              hipStream_t stream) {
    const float* x  = (const float*)d_in[0];
    const float* Wq = (const float*)d_in[1];
    const float* Wk = (const float*)d_in[2];
    const float* Wv = (const float*)d_in[3];
    const float* Wo = (const float*)d_in[4];
    float* out = (float*)d_out;

    const size_t n_x = (size_t)BL * DD;   // 8.4M
    const size_t n_w = (size_t)DD * DD;   // 1.05M
    short* xb  = (short*)d_ws;
    short* Wqb = xb  + n_x;               // Wqb..Wob contiguous (cast4 relies on it)
    short* Wkb = Wqb + n_w;
    short* Wvb = Wkb + n_w;
    short* Wob = Wvb + n_w;
    short* Q   = Wob + n_w;
    short* K   = Q   + n_x;
    short* VTg = K   + n_x;               // V transposed: (B,H,Hd,L), key-permuted
    short* AOb = VTg + n_x;
    float2* tab = (float2*)(AOb + n_x);   // 65536 float2 = 512 KB

    rope_tab_kernel<<<256, 256, 0, stream>>>(tab);
    cast_kernel<<<n_x/2048, 256, 0, stream>>>(x, xb, (int)n_x);
    cast4_kernel<<<4*(n_w/2048), 256, 0, stream>>>(Wq, Wk, Wv, Wo, Wqb);

    qkv_mfma_kernel<<<1536, 256, 0, stream>>>(xb, Wqb, Wkb, Wvb, tab, Q, K, VTg);

    dim3 g2(BB*HH, LL/128);
    attn_kernel<<<g2, 256, 0, stream>>>(Q, K, VTg, AOb);

    oproj_mfma_kernel<<<512, 256, 0, stream>>>(AOb, Wob, out);
}

// Round 6
// 257.321 us; speedup vs baseline: 1.1947x; 1.1947x over previous
//
#include <hip/hip_runtime.h>
#include <math.h>

#define BB 4
#define LL 2048
#define DD 1024
#define HH 16
#define HD 64
#define BL (BB*LL)

typedef __attribute__((ext_vector_type(8))) short bf16x8;
typedef __attribute__((ext_vector_type(4))) short bf16x4;
typedef __attribute__((ext_vector_type(4))) float f32x4;

__device__ inline short f2bf(float f) {
    union { float f; unsigned u; } v; v.f = f;
    unsigned r = v.u + 0x7fffu + ((v.u >> 16) & 1u);   // RNE
    return (short)(r >> 16);
}

// pack two fp32 -> two bf16 (truncation; p>=0 so bias is benign, ~2^-9 rel)
// single v_perm_b32: D = {b.b3, b.b2, a.b3, a.b2}
__device__ inline unsigned pk_bf16(float a, float b) {
    union { float f; unsigned u; } x, y; x.f = a; y.f = b;
#if __has_builtin(__builtin_amdgcn_perm)
    return __builtin_amdgcn_perm(y.u, x.u, 0x07060302u);
#else
    return (x.u >> 16) | (y.u & 0xffff0000u);
#endif
}

__device__ inline float exp2x(float x) {
#if __has_builtin(__builtin_amdgcn_exp2f)
    return __builtin_amdgcn_exp2f(x);
#else
    return exp2f(x);
#endif
}

__device__ inline void gload_lds16(const void* g, void* l) {
    __builtin_amdgcn_global_load_lds(
        (const __attribute__((address_space(1))) unsigned int*)g,
        (__attribute__((address_space(3))) unsigned int*)l, 16, 0, 0);
}

// ---------------------------------------------------------------------------
// fp32 -> bf16 cast, 8 elem/thread.
// ---------------------------------------------------------------------------
__global__ __launch_bounds__(256) void cast_kernel(
    const float* __restrict__ in, short* __restrict__ out, int n)
{
    int i = (blockIdx.x * 256 + threadIdx.x) * 8;
    float4 a = *(const float4*)(in + i);
    float4 b = *(const float4*)(in + i + 4);
    bf16x8 o;
    o[0]=f2bf(a.x); o[1]=f2bf(a.y); o[2]=f2bf(a.z); o[3]=f2bf(a.w);
    o[4]=f2bf(b.x); o[5]=f2bf(b.y); o[6]=f2bf(b.z); o[7]=f2bf(b.w);
    *(bf16x8*)(out + i) = o;
}

// 4 weight matrices (contiguous dsts), one launch. grid = 4 * n_w/2048.
__global__ __launch_bounds__(256) void cast4_kernel(
    const float* __restrict__ w0, const float* __restrict__ w1,
    const float* __restrict__ w2, const float* __restrict__ w3,
    short* __restrict__ out)
{
    const int nw_blocks = (DD*DD) / 2048;
    int sel = blockIdx.x / nw_blocks;
    int blk = blockIdx.x % nw_blocks;
    const float* in = (sel == 0) ? w0 : (sel == 1) ? w1 : (sel == 2) ? w2 : w3;
    int i = (blk * 256 + threadIdx.x) * 8;
    float4 a = *(const float4*)(in + i);
    float4 b = *(const float4*)(in + i + 4);
    bf16x8 o;
    o[0]=f2bf(a.x); o[1]=f2bf(a.y); o[2]=f2bf(a.z); o[3]=f2bf(a.w);
    o[4]=f2bf(b.x); o[5]=f2bf(b.y); o[6]=f2bf(b.z); o[7]=f2bf(b.w);
    *(bf16x8*)(out + (size_t)sel * DD * DD + i) = o;
}

// ---------------------------------------------------------------------------
// RoPE table: tab[l*32 + f] = (cos, sin) of l * 10000^(-f/32), f=0..31.
// ---------------------------------------------------------------------------
__global__ __launch_bounds__(256) void rope_tab_kernel(float2* __restrict__ tab)
{
    int idx = blockIdx.x * 256 + threadIdx.x;
    int lq = idx >> 5, f = idx & 31;
    float inv = __expf((float)f * (-9.210340371976184f / 32.0f));
    float s, c;
    sincosf((float)lq * inv, &s, &c);
    tab[idx] = make_float2(c, s);
}

// ---------------------------------------------------------------------------
// Shared 128x128-tile bf16 MFMA K-loop (m97 2-barrier structure, 32 KB LDS).
// R11: XOR-swizzled LDS columns (rule #21: linear gload_lds dest +
// pre-swizzled GLOBAL source + swizzled read) — conflicts 1.9e7 -> 2.6e5.
// R12: callers pin __launch_bounds__(256,4) => VGPR cap 128. R11's extra
// swizzle-address regs pushed the unified VGPR file to 132, crossing the
// 128 cliff (occupancy 19.6 -> 11%) and costing more than the conflicts.
// ---------------------------------------------------------------------------
__device__ inline void gemm_bt_128(const short* __restrict__ A,
                                   const short* __restrict__ B,
                                   short* Ash, short* Bsh,
                                   int i0, int n0, f32x4 (&acc)[4][4])
{
    const int t  = threadIdx.x;
    const int w  = t >> 6;
    const int l  = t & 63;
    const int g  = (t >> 4) & 3;
    const int ln = t & 15;
    const int rh = (w >> 1) * 64;
    const int ch = (w & 1) * 64;
    const int srow = w * 8 + (l >> 3);
    const int skol = ((l & 7) ^ (l >> 3)) * 8;   // source col swizzled by row&7
    const int rsw  = 8 * (ln & 7);               // read-side XOR key (row&7 == ln&7)

    for (int k0 = 0; k0 < DD; k0 += 64) {
        __syncthreads();
        const short* ga = A + (size_t)(i0 + srow) * DD + k0 + skol;
        const short* gb = B + (size_t)(n0 + srow) * DD + k0 + skol;
        short* la = Ash + w * 512;   // wave-uniform base
        short* lb = Bsh + w * 512;
        #pragma unroll
        for (int j = 0; j < 4; ++j) {
            gload_lds16(ga + j * 32 * DD, la + j * 2048);
            gload_lds16(gb + j * 32 * DD, lb + j * 2048);
        }
        __syncthreads();

        #pragma unroll
        for (int kk = 0; kk < 2; ++kk) {
            bf16x8 af[4], bfr[4];
            #pragma unroll
            for (int mi = 0; mi < 4; ++mi)
                af[mi] = *(const bf16x8*)(Ash + (rh + mi*16 + ln)*64 + ((kk*32 + 8*g) ^ rsw));
            #pragma unroll
            for (int nj = 0; nj < 4; ++nj)
                bfr[nj] = *(const bf16x8*)(Bsh + (ch + nj*16 + ln)*64 + ((kk*32 + 8*g) ^ rsw));
            #pragma unroll
            for (int mi = 0; mi < 4; ++mi)
                #pragma unroll
                for (int nj = 0; nj < 4; ++nj)
                    acc[mi][nj] = __builtin_amdgcn_mfma_f32_16x16x32_bf16(
                        af[mi], bfr[nj], acc[mi][nj], 0, 0, 0);
        }
    }
}

// ---------------------------------------------------------------------------
// Kernel 1: QKV projection + RoPE. 1-D grid 1536, XCD-aware decode:
// xcd r = gid&7 owns i-tiles r*8..r*8+7 (2 MB of x stays in that XCD's L2)
// and iterates all 24 (n,z) W-tiles (W-tile reused back-to-back).
// z=0/1: Q/K roped via table, Q scaled 0.125*log2(e), layout (B,H,L,Hd).
// z=2: V transposed (B,H,Hd,L) via two-pass LDS transpose. V keys are
// bit-permuted within each 64-key tile (key' [5:4]=g,[3]=hb,[2]=a,[1:0]=r
// of key = 32hb+16a+4g+r) so attn's PV B-frags are single b128 LDS reads.
// __launch_bounds__(256,4): cap VGPR at 128 (see gemm_bt_128 R12 note).
// ---------------------------------------------------------------------------
__global__ __launch_bounds__(256, 4) void qkv_mfma_kernel(
    const short* __restrict__ xb, const short* __restrict__ Wqb,
    const short* __restrict__ Wkb, const short* __restrict__ Wvb,
    const float2* __restrict__ rope_tab,
    short* __restrict__ Qo, short* __restrict__ Ko, short* __restrict__ Vo)
{
    __shared__ short Ash[128*64];
    __shared__ short Bsh[128*64];

    const int gid = blockIdx.x;
    const int r8  = gid & 7;           // XCD slot (round-robin heuristic)
    const int u   = gid >> 3;          // 0..191
    const int i_idx = r8 * 8 + (u & 7);      // 0..63
    const int nz  = u >> 3;                  // 0..23
    const int n_idx = nz & 7;                // 0..7
    const int z   = nz >> 3;                 // 0..2

    const short* Wm = (z == 0) ? Wqb : ((z == 1) ? Wkb : Wvb);
    const int i0 = i_idx * 128;
    const int n0 = n_idx * 128;

    f32x4 acc[4][4];
    #pragma unroll
    for (int mi = 0; mi < 4; ++mi)
        #pragma unroll
        for (int nj = 0; nj < 4; ++nj) acc[mi][nj] = (f32x4){0.f,0.f,0.f,0.f};

    gemm_bt_128(xb, Wm, Ash, Bsh, i0, n0, acc);

    const int t  = threadIdx.x;
    const int w  = t >> 6;
    const int g  = (t >> 4) & 3;
    const int ln = t & 15;
    const int rh = (w >> 1) * 64;

    if (z == 2) {
        // two passes over heads; buf[64 d][136 seq-stride] spans Ash..Bsh.
        short* buf = Ash;
        const int b = i0 >> 11, l0 = i0 & (LL - 1);
        const int d = t >> 2;
        const int c = t & 3;
        #pragma unroll
        for (int hp = 0; hp < 2; ++hp) {
            __syncthreads();
            if ((w & 1) == hp) {
                #pragma unroll
                for (int nj = 0; nj < 4; ++nj)
                    #pragma unroll
                    for (int mi = 0; mi < 4; ++mi)
                        #pragma unroll
                        for (int r = 0; r < 4; ++r)
                            buf[(nj*16 + ln)*136 + rh + mi*16 + 4*g + r]
                                = f2bf(acc[mi][nj][r]);
            }
            __syncthreads();
            short* dst = Vo + ((size_t)((b*HH + n_idx*2 + hp)*HD + d)) * LL + l0;
            // permuted store: global key base = 8c + 32j (within 128-row l0);
            // tile tb = 64*(j>>1), hb = j&1, a = c>>1, g0 = 2*(c&1);
            // keys k0..k0+3 -> key' 16*g0+8*hb+4*a..+3 ; k0+4..k0+7 -> g0+1.
            #pragma unroll
            for (int j = 0; j < 4; ++j) {
                const short* src = buf + d*136 + c*8 + j*32;
                bf16x4 lo = *(const bf16x4*)(src);
                bf16x4 hi = *(const bf16x4*)(src + 4);
                const int tb = (j >> 1) * 64;
                const int hb = j & 1;
                const int aa = c >> 1;
                const int g0 = (c & 1) * 2;
                *(bf16x4*)(dst + tb + g0*16       + hb*8 + aa*4) = lo;
                *(bf16x4*)(dst + tb + (g0+1)*16   + hb*8 + aa*4) = hi;
            }
        }
    } else {
        const int h = n_idx * 2 + (w & 1);
        short* Om = (z == 0) ? Qo : Ko;
        // Q: 1/sqrt(64) * log2(e) so scores feed exp2 directly
        const float sc = (z == 0) ? 0.180336880111112f : 1.0f;
        #pragma unroll
        for (int mi = 0; mi < 4; ++mi)
            #pragma unroll
            for (int r = 0; r < 4; ++r) {
                int i = i0 + rh + mi*16 + 4*g + r;
                int b = i >> 11, lq = i & (LL - 1);
                float2 cs0 = rope_tab[lq*32 + ln];        // freq ln
                float2 cs1 = rope_tab[lq*32 + ln + 16];   // freq ln+16
                float r0 = (acc[mi][0][r]*cs0.x - acc[mi][2][r]*cs0.y) * sc;
                float r2 = (acc[mi][2][r]*cs0.x + acc[mi][0][r]*cs0.y) * sc;
                float r1 = (acc[mi][1][r]*cs1.x - acc[mi][3][r]*cs1.y) * sc;
                float r3 = (acc[mi][3][r]*cs1.x + acc[mi][1][r]*cs1.y) * sc;
                size_t base = ((size_t)(b*HH + h) * LL + lq) * HD;
                Om[base + ln     ] = f2bf(r0);
                Om[base + ln + 16] = f2bf(r1);
                Om[base + ln + 32] = f2bf(r2);
                Om[base + ln + 48] = f2bf(r3);
            }
    }
}

// ---------------------------------------------------------------------------
// Kernel 2: bf16 MFMA flash attention (unchanged from R9).
// grid = (B*H, L/128): bh on x => the 16 q-tile blocks sharing one bh get
// gid == bh (mod 8) -> same XCD -> K/V stay in one L2.
//  (a) l-sum via MFMA ones-trick (lsum element r == O row 4g+r).
//  (b) VT global layout key-bit-permuted -> PV B-frag = one b128 LDS read.
//  (c) pk_bf16 = single v_perm_b32.
// ---------------------------------------------------------------------------
__global__ __launch_bounds__(256) void attn_kernel(
    const short* __restrict__ Q, const short* __restrict__ K,
    const short* __restrict__ VT, short* __restrict__ AO)
{
    __shared__ short Ksh[64*72];   // [key][d]
    __shared__ short VTs[64*72];   // [d][key']  (key' = permuted key)

    const int t  = threadIdx.x;
    const int w  = t >> 6;
    const int l  = t & 63;
    const int g  = l >> 4;
    const int ln = l & 15;

    const int bh = blockIdx.x;
    const int q0 = blockIdx.y * 128;
    const short* Qb  = Q  + ((size_t)bh * LL + q0 + w*32) * HD;
    const short* Kb  = K  + (size_t)bh * LL * HD;
    const short* VTb = VT + (size_t)bh * HD * LL;

    // Q B-frags: [n=q=ln][k=d=8g+j(+32)]
    bf16x8 qb[2][2];
    #pragma unroll
    for (int qi = 0; qi < 2; ++qi) {
        qb[qi][0] = *(const bf16x8*)(Qb + (size_t)(qi*16 + ln)*HD + 8*g);
        qb[qi][1] = *(const bf16x8*)(Qb + (size_t)(qi*16 + ln)*HD + 32 + 8*g);
    }

    const bf16x8 ONES = { (short)0x3F80, (short)0x3F80, (short)0x3F80, (short)0x3F80,
                          (short)0x3F80, (short)0x3F80, (short)0x3F80, (short)0x3F80 };

    f32x4 O[2][4];                 // O[qi][db]: row q=4g+r, col d=db*16+ln
    #pragma unroll
    for (int qi = 0; qi < 2; ++qi)
        #pragma unroll
        for (int db = 0; db < 4; ++db) O[qi][db] = (f32x4){0.f,0.f,0.f,0.f};
    f32x4 lsum[2];                 // lsum[qi][r] = l for row q=4g+r (any ln)
    lsum[0] = (f32x4){0.f,0.f,0.f,0.f};
    lsum[1] = (f32x4){0.f,0.f,0.f,0.f};

    const int sr = t >> 2;          // staging row (key for Ksh, d for VTs)
    const int sc = (t & 3) << 4;    // staging col chunk

    for (int kt = 0; kt < LL; kt += 64) {
        bf16x8 k0 = *(const bf16x8*)(Kb  + (size_t)(kt + sr)*HD + sc);
        bf16x8 k1 = *(const bf16x8*)(Kb  + (size_t)(kt + sr)*HD + sc + 8);
        bf16x8 v0 = *(const bf16x8*)(VTb + (size_t)sr*LL + kt + sc);
        bf16x8 v1 = *(const bf16x8*)(VTb + (size_t)sr*LL + kt + sc + 8);
        __syncthreads();           // previous tile fully consumed
        *(bf16x8*)(Ksh + sr*72 + sc)     = k0;
        *(bf16x8*)(Ksh + sr*72 + sc + 8) = k1;
        *(bf16x8*)(VTs + sr*72 + sc)     = v0;
        *(bf16x8*)(VTs + sr*72 + sc + 8) = v1;
        __syncthreads();

        unsigned pf[2][4][2];      // [qi][kb]: keys (4g,4g+1),(4g+2,4g+3)
        #pragma unroll
        for (int kb = 0; kb < 4; ++kb) {
            // K A-frags: [m=key=kb*16+ln][k=d]
            bf16x8 ka0 = *(const bf16x8*)(Ksh + (kb*16 + ln)*72 + 8*g);
            bf16x8 ka1 = *(const bf16x8*)(Ksh + (kb*16 + ln)*72 + 32 + 8*g);
            #pragma unroll
            for (int qi = 0; qi < 2; ++qi) {
                f32x4 S = (f32x4){0.f,0.f,0.f,0.f};
                S = __builtin_amdgcn_mfma_f32_16x16x32_bf16(ka0, qb[qi][0], S, 0, 0, 0);
                S = __builtin_amdgcn_mfma_f32_16x16x32_bf16(ka1, qb[qi][1], S, 0, 0, 0);
                float p0 = exp2x(S[0]), p1 = exp2x(S[1]);
                float p2 = exp2x(S[2]), p3 = exp2x(S[3]);
                pf[qi][kb][0] = pk_bf16(p0, p1);
                pf[qi][kb][1] = pk_bf16(p2, p3);
            }
        }

        // P A-frags for PV/lsum: slot (g,j) <-> key 32hb + 16*(j>>2) + 4g + (j&3)
        bf16x8 pa[2][2];
        #pragma unroll
        for (int qi = 0; qi < 2; ++qi)
            #pragma unroll
            for (int hb = 0; hb < 2; ++hb) {
                union { unsigned u[4]; bf16x8 v; } a;
                a.u[0] = pf[qi][2*hb][0];   a.u[1] = pf[qi][2*hb][1];
                a.u[2] = pf[qi][2*hb+1][0]; a.u[3] = pf[qi][2*hb+1][1];
                pa[qi][hb] = a.v;
            }

        // l-sum: one MFMA per (hb,qi) with all-ones B
        #pragma unroll
        for (int hb = 0; hb < 2; ++hb) {
            lsum[0] = __builtin_amdgcn_mfma_f32_16x16x32_bf16(pa[0][hb], ONES, lsum[0], 0, 0, 0);
            lsum[1] = __builtin_amdgcn_mfma_f32_16x16x32_bf16(pa[1][hb], ONES, lsum[1], 0, 0, 0);
        }

        // PV via 16x16x32: B-frag = one b128 from permuted VTs
        #pragma unroll
        for (int hb = 0; hb < 2; ++hb) {
            #pragma unroll
            for (int db = 0; db < 4; ++db) {
                bf16x8 vf = *(const bf16x8*)(VTs + (db*16 + ln)*72 + 16*g + 8*hb);
                O[0][db] = __builtin_amdgcn_mfma_f32_16x16x32_bf16(pa[0][hb], vf, O[0][db], 0, 0, 0);
                O[1][db] = __builtin_amdgcn_mfma_f32_16x16x32_bf16(pa[1][hb], vf, O[1][db], 0, 0, 0);
            }
        }
    }

    // epilogue: lsum[qi][r] is exactly l for row q=4g+r — no shuffles.
    const int b = bh >> 4, h = bh & 15;
    #pragma unroll
    for (int qi = 0; qi < 2; ++qi) {
        #pragma unroll
        for (int r = 0; r < 4; ++r) {
            float inv = 1.0f / lsum[qi][r];
            int q = q0 + w*32 + qi*16 + 4*g + r;
            size_t base = ((size_t)(b*LL + q)) * DD + h*HD;
            #pragma unroll
            for (int db = 0; db < 4; ++db)
                AO[base + db*16 + ln] = f2bf(O[qi][db][r] * inv);
        }
    }
}

// ---------------------------------------------------------------------------
// Kernel 3: output projection. 1-D grid 512, same XCD-aware decode as qkv:
// each XCD owns 8 i-tiles of A + iterates the 8 Wo n-tiles.
// __launch_bounds__(256,4): cap VGPR at 128 (see gemm_bt_128 R12 note).
// ---------------------------------------------------------------------------
__global__ __launch_bounds__(256, 4) void oproj_mfma_kernel(
    const short* __restrict__ A, const short* __restrict__ Wob,
    float* __restrict__ out)
{
    __shared__ short Ash[128*64];
    __shared__ short Bsh[128*64];

    const int gid = blockIdx.x;
    const int r8  = gid & 7;
    const int u   = gid >> 3;              // 0..63
    const int i_idx = r8 * 8 + (u & 7);    // 0..63
    const int n_idx = u >> 3;              // 0..7
    const int i0 = i_idx * 128;
    const int n0 = n_idx * 128;

    f32x4 acc[4][4];
    #pragma unroll
    for (int mi = 0; mi < 4; ++mi)
        #pragma unroll
        for (int nj = 0; nj < 4; ++nj) acc[mi][nj] = (f32x4){0.f,0.f,0.f,0.f};

    gemm_bt_128(A, Wob, Ash, Bsh, i0, n0, acc);

    const int t  = threadIdx.x;
    const int w  = t >> 6;
    const int g  = (t >> 4) & 3;
    const int ln = t & 15;
    const int rh = (w >> 1) * 64;
    const int ch = (w & 1) * 64;

    #pragma unroll
    for (int mi = 0; mi < 4; ++mi)
        #pragma unroll
        for (int r = 0; r < 4; ++r) {
            size_t base = (size_t)(i0 + rh + mi*16 + 4*g + r) * DD + n0 + ch;
            #pragma unroll
            for (int nj = 0; nj < 4; ++nj)
                out[base + nj*16 + ln] = acc[mi][nj][r];
        }
}

// ---------------------------------------------------------------------------
extern "C" void kernel_launch(void* const* d_in, const int* in_sizes, int n_in,
                              void* d_out, int out_size, void* d_ws, size_t ws_size,
                              hipStream_t stream) {
    const float* x  = (const float*)d_in[0];
    const float* Wq = (const float*)d_in[1];
    const float* Wk = (const float*)d_in[2];
    const float* Wv = (const float*)d_in[3];
    const float* Wo = (const float*)d_in[4];
    float* out = (float*)d_out;

    const size_t n_x = (size_t)BL * DD;   // 8.4M
    const size_t n_w = (size_t)DD * DD;   // 1.05M
    short* xb  = (short*)d_ws;
    short* Wqb = xb  + n_x;               // Wqb..Wob contiguous (cast4 relies on it)
    short* Wkb = Wqb + n_w;
    short* Wvb = Wkb + n_w;
    short* Wob = Wvb + n_w;
    short* Q   = Wob + n_w;
    short* K   = Q   + n_x;
    short* VTg = K   + n_x;               // V transposed: (B,H,Hd,L), key-permuted
    short* AOb = VTg + n_x;
    float2* tab = (float2*)(AOb + n_x);   // 65536 float2 = 512 KB

    rope_tab_kernel<<<256, 256, 0, stream>>>(tab);
    cast_kernel<<<n_x/2048, 256, 0, stream>>>(x, xb, (int)n_x);
    cast4_kernel<<<4*(n_w/2048), 256, 0, stream>>>(Wq, Wk, Wv, Wo, Wqb);

    qkv_mfma_kernel<<<1536, 256, 0, stream>>>(xb, Wqb, Wkb, Wvb, tab, Q, K, VTg);

    dim3 g2(BB*HH, LL/128);
    attn_kernel<<<g2, 256, 0, stream>>>(Q, K, VTg, AOb);

    oproj_mfma_kernel<<<512, 256, 0, stream>>>(AOb, Wob, out);
}

// Round 7
// 254.030 us; speedup vs baseline: 1.2102x; 1.0130x over previous
//
#include <hip/hip_runtime.h>
#include <math.h>

#define BB 4
#define LL 2048
#define DD 1024
#define HH 16
#define HD 64
#define BL (BB*LL)

typedef __attribute__((ext_vector_type(8))) short bf16x8;
typedef __attribute__((ext_vector_type(4))) short bf16x4;
typedef __attribute__((ext_vector_type(4))) float f32x4;

__device__ inline short f2bf(float f) {
    union { float f; unsigned u; } v; v.f = f;
    unsigned r = v.u + 0x7fffu + ((v.u >> 16) & 1u);   // RNE
    return (short)(r >> 16);
}

// pack two fp32 -> two bf16 (truncation; p>=0 so bias is benign, ~2^-9 rel)
// single v_perm_b32: D = {b.b3, b.b2, a.b3, a.b2}
__device__ inline unsigned pk_bf16(float a, float b) {
    union { float f; unsigned u; } x, y; x.f = a; y.f = b;
#if __has_builtin(__builtin_amdgcn_perm)
    return __builtin_amdgcn_perm(y.u, x.u, 0x07060302u);
#else
    return (x.u >> 16) | (y.u & 0xffff0000u);
#endif
}

__device__ inline float exp2x(float x) {
#if __has_builtin(__builtin_amdgcn_exp2f)
    return __builtin_amdgcn_exp2f(x);
#else
    return exp2f(x);
#endif
}

__device__ inline void gload_lds16(const void* g, void* l) {
    __builtin_amdgcn_global_load_lds(
        (const __attribute__((address_space(1))) unsigned int*)g,
        (__attribute__((address_space(3))) unsigned int*)l, 16, 0, 0);
}

// ---------------------------------------------------------------------------
// R13: fused prep kernel — rope table + x cast + 4-weight cast in ONE launch
// (they are mutually independent; 3 launches -> 1 saves ~2 gaps of ~10 us).
// Block ranges: [0,4096) x-cast, [4096,6144) weight cast4, [6144,6400) rope.
// ---------------------------------------------------------------------------
#define NB_CASTX ((BL*DD)/2048)         // 4096
#define NB_CASTW (4*((DD*DD)/2048))     // 2048
#define NB_ROPE  256

__global__ __launch_bounds__(256) void prep_kernel(
    const float* __restrict__ x,
    const float* __restrict__ w0, const float* __restrict__ w1,
    const float* __restrict__ w2, const float* __restrict__ w3,
    short* __restrict__ xb, short* __restrict__ wout,
    float2* __restrict__ tab)
{
    const int bid = blockIdx.x;
    if (bid < NB_CASTX) {
        int i = (bid * 256 + threadIdx.x) * 8;
        float4 a = *(const float4*)(x + i);
        float4 b = *(const float4*)(x + i + 4);
        bf16x8 o;
        o[0]=f2bf(a.x); o[1]=f2bf(a.y); o[2]=f2bf(a.z); o[3]=f2bf(a.w);
        o[4]=f2bf(b.x); o[5]=f2bf(b.y); o[6]=f2bf(b.z); o[7]=f2bf(b.w);
        *(bf16x8*)(xb + i) = o;
    } else if (bid < NB_CASTX + NB_CASTW) {
        const int nw_blocks = (DD*DD) / 2048;    // 512
        int b2  = bid - NB_CASTX;
        int sel = b2 / nw_blocks;
        int blk = b2 % nw_blocks;
        const float* in = (sel == 0) ? w0 : (sel == 1) ? w1 : (sel == 2) ? w2 : w3;
        int i = (blk * 256 + threadIdx.x) * 8;
        float4 a = *(const float4*)(in + i);
        float4 b = *(const float4*)(in + i + 4);
        bf16x8 o;
        o[0]=f2bf(a.x); o[1]=f2bf(a.y); o[2]=f2bf(a.z); o[3]=f2bf(a.w);
        o[4]=f2bf(b.x); o[5]=f2bf(b.y); o[6]=f2bf(b.z); o[7]=f2bf(b.w);
        *(bf16x8*)(wout + (size_t)sel * DD * DD + i) = o;
    } else {
        int idx = (bid - NB_CASTX - NB_CASTW) * 256 + threadIdx.x;
        int lq = idx >> 5, f = idx & 31;
        float inv = __expf((float)f * (-9.210340371976184f / 32.0f));
        float s, c;
        sincosf((float)lq * inv, &s, &c);
        tab[idx] = make_float2(c, s);
    }
}

// ---------------------------------------------------------------------------
// Shared 128x128-tile bf16 MFMA K-loop (m97 2-barrier structure, 32 KB LDS).
// R11: XOR-swizzled LDS columns (rule #21: linear gload_lds dest +
// pre-swizzled GLOBAL source + swizzled read) — conflicts 1.9e7 -> 2.6e5.
// R12: callers pin __launch_bounds__(256,4) => VGPR cap 128 (132 crossed the
// 128 occupancy cliff: 19.6 -> 11%).
// ---------------------------------------------------------------------------
__device__ inline void gemm_bt_128(const short* __restrict__ A,
                                   const short* __restrict__ B,
                                   short* Ash, short* Bsh,
                                   int i0, int n0, f32x4 (&acc)[4][4])
{
    const int t  = threadIdx.x;
    const int w  = t >> 6;
    const int l  = t & 63;
    const int g  = (t >> 4) & 3;
    const int ln = t & 15;
    const int rh = (w >> 1) * 64;
    const int ch = (w & 1) * 64;
    const int srow = w * 8 + (l >> 3);
    const int skol = ((l & 7) ^ (l >> 3)) * 8;   // source col swizzled by row&7
    const int rsw  = 8 * (ln & 7);               // read-side XOR key (row&7 == ln&7)

    for (int k0 = 0; k0 < DD; k0 += 64) {
        __syncthreads();
        const short* ga = A + (size_t)(i0 + srow) * DD + k0 + skol;
        const short* gb = B + (size_t)(n0 + srow) * DD + k0 + skol;
        short* la = Ash + w * 512;   // wave-uniform base
        short* lb = Bsh + w * 512;
        #pragma unroll
        for (int j = 0; j < 4; ++j) {
            gload_lds16(ga + j * 32 * DD, la + j * 2048);
            gload_lds16(gb + j * 32 * DD, lb + j * 2048);
        }
        __syncthreads();

        #pragma unroll
        for (int kk = 0; kk < 2; ++kk) {
            bf16x8 af[4], bfr[4];
            #pragma unroll
            for (int mi = 0; mi < 4; ++mi)
                af[mi] = *(const bf16x8*)(Ash + (rh + mi*16 + ln)*64 + ((kk*32 + 8*g) ^ rsw));
            #pragma unroll
            for (int nj = 0; nj < 4; ++nj)
                bfr[nj] = *(const bf16x8*)(Bsh + (ch + nj*16 + ln)*64 + ((kk*32 + 8*g) ^ rsw));
            #pragma unroll
            for (int mi = 0; mi < 4; ++mi)
                #pragma unroll
                for (int nj = 0; nj < 4; ++nj)
                    acc[mi][nj] = __builtin_amdgcn_mfma_f32_16x16x32_bf16(
                        af[mi], bfr[nj], acc[mi][nj], 0, 0, 0);
        }
    }
}

// ---------------------------------------------------------------------------
// Kernel 1: QKV projection + RoPE. 1-D grid 1536, XCD-aware decode:
// xcd r = gid&7 owns i-tiles r*8..r*8+7 (2 MB of x stays in that XCD's L2)
// and iterates all 24 (n,z) W-tiles (W-tile reused back-to-back).
// z=0/1: Q/K roped via table, Q scaled 0.125*log2(e), layout (B,H,L,Hd).
// z=2: V transposed (B,H,Hd,L) via two-pass LDS transpose. V keys are
// bit-permuted within each 64-key tile (key' [5:4]=g,[3]=hb,[2]=a,[1:0]=r
// of key = 32hb+16a+4g+r) so attn's PV B-frags are single b128 LDS reads.
// ---------------------------------------------------------------------------
__global__ __launch_bounds__(256, 4) void qkv_mfma_kernel(
    const short* __restrict__ xb, const short* __restrict__ Wqb,
    const short* __restrict__ Wkb, const short* __restrict__ Wvb,
    const float2* __restrict__ rope_tab,
    short* __restrict__ Qo, short* __restrict__ Ko, short* __restrict__ Vo)
{
    __shared__ short Ash[128*64];
    __shared__ short Bsh[128*64];

    const int gid = blockIdx.x;
    const int r8  = gid & 7;           // XCD slot (round-robin heuristic)
    const int u   = gid >> 3;          // 0..191
    const int i_idx = r8 * 8 + (u & 7);      // 0..63
    const int nz  = u >> 3;                  // 0..23
    const int n_idx = nz & 7;                // 0..7
    const int z   = nz >> 3;                 // 0..2

    const short* Wm = (z == 0) ? Wqb : ((z == 1) ? Wkb : Wvb);
    const int i0 = i_idx * 128;
    const int n0 = n_idx * 128;

    f32x4 acc[4][4];
    #pragma unroll
    for (int mi = 0; mi < 4; ++mi)
        #pragma unroll
        for (int nj = 0; nj < 4; ++nj) acc[mi][nj] = (f32x4){0.f,0.f,0.f,0.f};

    gemm_bt_128(xb, Wm, Ash, Bsh, i0, n0, acc);

    const int t  = threadIdx.x;
    const int w  = t >> 6;
    const int g  = (t >> 4) & 3;
    const int ln = t & 15;
    const int rh = (w >> 1) * 64;

    if (z == 2) {
        // two passes over heads; buf[64 d][136 seq-stride] spans Ash..Bsh.
        short* buf = Ash;
        const int b = i0 >> 11, l0 = i0 & (LL - 1);
        const int d = t >> 2;
        const int c = t & 3;
        #pragma unroll
        for (int hp = 0; hp < 2; ++hp) {
            __syncthreads();
            if ((w & 1) == hp) {
                #pragma unroll
                for (int nj = 0; nj < 4; ++nj)
                    #pragma unroll
                    for (int mi = 0; mi < 4; ++mi)
                        #pragma unroll
                        for (int r = 0; r < 4; ++r)
                            buf[(nj*16 + ln)*136 + rh + mi*16 + 4*g + r]
                                = f2bf(acc[mi][nj][r]);
            }
            __syncthreads();
            short* dst = Vo + ((size_t)((b*HH + n_idx*2 + hp)*HD + d)) * LL + l0;
            // permuted store: global key base = 8c + 32j (within 128-row l0);
            // tile tb = 64*(j>>1), hb = j&1, a = c>>1, g0 = 2*(c&1);
            // keys k0..k0+3 -> key' 16*g0+8*hb+4*a..+3 ; k0+4..k0+7 -> g0+1.
            #pragma unroll
            for (int j = 0; j < 4; ++j) {
                const short* src = buf + d*136 + c*8 + j*32;
                bf16x4 lo = *(const bf16x4*)(src);
                bf16x4 hi = *(const bf16x4*)(src + 4);
                const int tb = (j >> 1) * 64;
                const int hb = j & 1;
                const int aa = c >> 1;
                const int g0 = (c & 1) * 2;
                *(bf16x4*)(dst + tb + g0*16       + hb*8 + aa*4) = lo;
                *(bf16x4*)(dst + tb + (g0+1)*16   + hb*8 + aa*4) = hi;
            }
        }
    } else {
        const int h = n_idx * 2 + (w & 1);
        short* Om = (z == 0) ? Qo : Ko;
        // Q: 1/sqrt(64) * log2(e) so scores feed exp2 directly
        const float sc = (z == 0) ? 0.180336880111112f : 1.0f;
        #pragma unroll
        for (int mi = 0; mi < 4; ++mi)
            #pragma unroll
            for (int r = 0; r < 4; ++r) {
                int i = i0 + rh + mi*16 + 4*g + r;
                int b = i >> 11, lq = i & (LL - 1);
                float2 cs0 = rope_tab[lq*32 + ln];        // freq ln
                float2 cs1 = rope_tab[lq*32 + ln + 16];   // freq ln+16
                float r0 = (acc[mi][0][r]*cs0.x - acc[mi][2][r]*cs0.y) * sc;
                float r2 = (acc[mi][2][r]*cs0.x + acc[mi][0][r]*cs0.y) * sc;
                float r1 = (acc[mi][1][r]*cs1.x - acc[mi][3][r]*cs1.y) * sc;
                float r3 = (acc[mi][3][r]*cs1.x + acc[mi][1][r]*cs1.y) * sc;
                size_t base = ((size_t)(b*HH + h) * LL + lq) * HD;
                Om[base + ln     ] = f2bf(r0);
                Om[base + ln + 16] = f2bf(r1);
                Om[base + ln + 32] = f2bf(r2);
                Om[base + ln + 48] = f2bf(r3);
            }
    }
}

// ---------------------------------------------------------------------------
// Kernel 2: bf16 MFMA flash attention.
// grid = (B*H, L/128): bh on x => the 16 q-tile blocks sharing one bh get
// gid == bh (mod 8) -> same XCD -> K/V stay in one L2.
//  (a) l-sum via MFMA ones-trick (lsum element r == O row 4g+r).
//  (b) VT global layout key-bit-permuted -> PV B-frag = one b128 LDS read.
//  (c) pk_bf16 = single v_perm_b32.
// R13 (d): one-ahead staging prefetch (T14): K/V loads for tile kt+64 are
// issued AFTER the LDS writes of tile kt and BEFORE compute(kt) — the
// vmcnt wait on them lands at the NEXT iteration's writes, so L2 latency
// (~200cy) hides under a full compute phase even for the barrier-critical
// wave. Old order issued loads right before the wait. +16 VGPR (60->~76),
// no cliff; occupancy is grid-limited at 4 blocks/CU.
// ---------------------------------------------------------------------------
__global__ __launch_bounds__(256) void attn_kernel(
    const short* __restrict__ Q, const short* __restrict__ K,
    const short* __restrict__ VT, short* __restrict__ AO)
{
    __shared__ short Ksh[64*72];   // [key][d]
    __shared__ short VTs[64*72];   // [d][key']  (key' = permuted key)

    const int t  = threadIdx.x;
    const int w  = t >> 6;
    const int l  = t & 63;
    const int g  = l >> 4;
    const int ln = l & 15;

    const int bh = blockIdx.x;
    const int q0 = blockIdx.y * 128;
    const short* Qb  = Q  + ((size_t)bh * LL + q0 + w*32) * HD;
    const short* Kb  = K  + (size_t)bh * LL * HD;
    const short* VTb = VT + (size_t)bh * HD * LL;

    // Q B-frags: [n=q=ln][k=d=8g+j(+32)]
    bf16x8 qb[2][2];
    #pragma unroll
    for (int qi = 0; qi < 2; ++qi) {
        qb[qi][0] = *(const bf16x8*)(Qb + (size_t)(qi*16 + ln)*HD + 8*g);
        qb[qi][1] = *(const bf16x8*)(Qb + (size_t)(qi*16 + ln)*HD + 32 + 8*g);
    }

    const bf16x8 ONES = { (short)0x3F80, (short)0x3F80, (short)0x3F80, (short)0x3F80,
                          (short)0x3F80, (short)0x3F80, (short)0x3F80, (short)0x3F80 };

    f32x4 O[2][4];                 // O[qi][db]: row q=4g+r, col d=db*16+ln
    #pragma unroll
    for (int qi = 0; qi < 2; ++qi)
        #pragma unroll
        for (int db = 0; db < 4; ++db) O[qi][db] = (f32x4){0.f,0.f,0.f,0.f};
    f32x4 lsum[2];                 // lsum[qi][r] = l for row q=4g+r (any ln)
    lsum[0] = (f32x4){0.f,0.f,0.f,0.f};
    lsum[1] = (f32x4){0.f,0.f,0.f,0.f};

    const int sr = t >> 2;          // staging row (key for Ksh, d for VTs)
    const int sc = (t & 3) << 4;    // staging col chunk

    // preload tile 0 into regs
    bf16x8 k0 = *(const bf16x8*)(Kb  + (size_t)sr*HD + sc);
    bf16x8 k1 = *(const bf16x8*)(Kb  + (size_t)sr*HD + sc + 8);
    bf16x8 v0 = *(const bf16x8*)(VTb + (size_t)sr*LL + sc);
    bf16x8 v1 = *(const bf16x8*)(VTb + (size_t)sr*LL + sc + 8);

    for (int kt = 0; kt < LL; kt += 64) {
        __syncthreads();           // previous tile fully consumed
        *(bf16x8*)(Ksh + sr*72 + sc)     = k0;
        *(bf16x8*)(Ksh + sr*72 + sc + 8) = k1;
        *(bf16x8*)(VTs + sr*72 + sc)     = v0;
        *(bf16x8*)(VTs + sr*72 + sc + 8) = v1;
        if (kt + 64 < LL) {        // prefetch next tile; waited at next writes
            k0 = *(const bf16x8*)(Kb  + (size_t)(kt + 64 + sr)*HD + sc);
            k1 = *(const bf16x8*)(Kb  + (size_t)(kt + 64 + sr)*HD + sc + 8);
            v0 = *(const bf16x8*)(VTb + (size_t)sr*LL + kt + 64 + sc);
            v1 = *(const bf16x8*)(VTb + (size_t)sr*LL + kt + 64 + sc + 8);
        }
        __syncthreads();

        unsigned pf[2][4][2];      // [qi][kb]: keys (4g,4g+1),(4g+2,4g+3)
        #pragma unroll
        for (int kb = 0; kb < 4; ++kb) {
            // K A-frags: [m=key=kb*16+ln][k=d]
            bf16x8 ka0 = *(const bf16x8*)(Ksh + (kb*16 + ln)*72 + 8*g);
            bf16x8 ka1 = *(const bf16x8*)(Ksh + (kb*16 + ln)*72 + 32 + 8*g);
            #pragma unroll
            for (int qi = 0; qi < 2; ++qi) {
                f32x4 S = (f32x4){0.f,0.f,0.f,0.f};
                S = __builtin_amdgcn_mfma_f32_16x16x32_bf16(ka0, qb[qi][0], S, 0, 0, 0);
                S = __builtin_amdgcn_mfma_f32_16x16x32_bf16(ka1, qb[qi][1], S, 0, 0, 0);
                float p0 = exp2x(S[0]), p1 = exp2x(S[1]);
                float p2 = exp2x(S[2]), p3 = exp2x(S[3]);
                pf[qi][kb][0] = pk_bf16(p0, p1);
                pf[qi][kb][1] = pk_bf16(p2, p3);
            }
        }

        // P A-frags for PV/lsum: slot (g,j) <-> key 32hb + 16*(j>>2) + 4g + (j&3)
        bf16x8 pa[2][2];
        #pragma unroll
        for (int qi = 0; qi < 2; ++qi)
            #pragma unroll
            for (int hb = 0; hb < 2; ++hb) {
                union { unsigned u[4]; bf16x8 v; } a;
                a.u[0] = pf[qi][2*hb][0];   a.u[1] = pf[qi][2*hb][1];
                a.u[2] = pf[qi][2*hb+1][0]; a.u[3] = pf[qi][2*hb+1][1];
                pa[qi][hb] = a.v;
            }

        // l-sum: one MFMA per (hb,qi) with all-ones B
        #pragma unroll
        for (int hb = 0; hb < 2; ++hb) {
            lsum[0] = __builtin_amdgcn_mfma_f32_16x16x32_bf16(pa[0][hb], ONES, lsum[0], 0, 0, 0);
            lsum[1] = __builtin_amdgcn_mfma_f32_16x16x32_bf16(pa[1][hb], ONES, lsum[1], 0, 0, 0);
        }

        // PV via 16x16x32: B-frag = one b128 from permuted VTs
        #pragma unroll
        for (int hb = 0; hb < 2; ++hb) {
            #pragma unroll
            for (int db = 0; db < 4; ++db) {
                bf16x8 vf = *(const bf16x8*)(VTs + (db*16 + ln)*72 + 16*g + 8*hb);
                O[0][db] = __builtin_amdgcn_mfma_f32_16x16x32_bf16(pa[0][hb], vf, O[0][db], 0, 0, 0);
                O[1][db] = __builtin_amdgcn_mfma_f32_16x16x32_bf16(pa[1][hb], vf, O[1][db], 0, 0, 0);
            }
        }
    }

    // epilogue: lsum[qi][r] is exactly l for row q=4g+r — no shuffles.
    const int b = bh >> 4, h = bh & 15;
    #pragma unroll
    for (int qi = 0; qi < 2; ++qi) {
        #pragma unroll
        for (int r = 0; r < 4; ++r) {
            float inv = 1.0f / lsum[qi][r];
            int q = q0 + w*32 + qi*16 + 4*g + r;
            size_t base = ((size_t)(b*LL + q)) * DD + h*HD;
            #pragma unroll
            for (int db = 0; db < 4; ++db)
                AO[base + db*16 + ln] = f2bf(O[qi][db][r] * inv);
        }
    }
}

// ---------------------------------------------------------------------------
// Kernel 3: output projection. 1-D grid 512, same XCD-aware decode as qkv:
// each XCD owns 8 i-tiles of A + iterates the 8 Wo n-tiles.
// ---------------------------------------------------------------------------
__global__ __launch_bounds__(256, 4) void oproj_mfma_kernel(
    const short* __restrict__ A, const short* __restrict__ Wob,
    float* __restrict__ out)
{
    __shared__ short Ash[128*64];
    __shared__ short Bsh[128*64];

    const int gid = blockIdx.x;
    const int r8  = gid & 7;
    const int u   = gid >> 3;              // 0..63
    const int i_idx = r8 * 8 + (u & 7);    // 0..63
    const int n_idx = u >> 3;              // 0..7
    const int i0 = i_idx * 128;
    const int n0 = n_idx * 128;

    f32x4 acc[4][4];
    #pragma unroll
    for (int mi = 0; mi < 4; ++mi)
        #pragma unroll
        for (int nj = 0; nj < 4; ++nj) acc[mi][nj] = (f32x4){0.f,0.f,0.f,0.f};

    gemm_bt_128(A, Wob, Ash, Bsh, i0, n0, acc);

    const int t  = threadIdx.x;
    const int w  = t >> 6;
    const int g  = (t >> 4) & 3;
    const int ln = t & 15;
    const int rh = (w >> 1) * 64;
    const int ch = (w & 1) * 64;

    #pragma unroll
    for (int mi = 0; mi < 4; ++mi)
        #pragma unroll
        for (int r = 0; r < 4; ++r) {
            size_t base = (size_t)(i0 + rh + mi*16 + 4*g + r) * DD + n0 + ch;
            #pragma unroll
            for (int nj = 0; nj < 4; ++nj)
                out[base + nj*16 + ln] = acc[mi][nj][r];
        }
}

// ---------------------------------------------------------------------------
extern "C" void kernel_launch(void* const* d_in, const int* in_sizes, int n_in,
                              void* d_out, int out_size, void* d_ws, size_t ws_size,
                              hipStream_t stream) {
    const float* x  = (const float*)d_in[0];
    const float* Wq = (const float*)d_in[1];
    const float* Wk = (const float*)d_in[2];
    const float* Wv = (const float*)d_in[3];
    const float* Wo = (const float*)d_in[4];
    float* out = (float*)d_out;

    const size_t n_x = (size_t)BL * DD;   // 8.4M
    const size_t n_w = (size_t)DD * DD;   // 1.05M
    short* xb  = (short*)d_ws;
    short* Wqb = xb  + n_x;               // Wqb..Wob contiguous (prep relies on it)
    short* Wkb = Wqb + n_w;
    short* Wvb = Wkb + n_w;
    short* Wob = Wvb + n_w;
    short* Q   = Wob + n_w;
    short* K   = Q   + n_x;
    short* VTg = K   + n_x;               // V transposed: (B,H,Hd,L), key-permuted
    short* AOb = VTg + n_x;
    float2* tab = (float2*)(AOb + n_x);   // 65536 float2 = 512 KB

    prep_kernel<<<NB_CASTX + NB_CASTW + NB_ROPE, 256, 0, stream>>>(
        x, Wq, Wk, Wv, Wo, xb, Wqb, tab);

    qkv_mfma_kernel<<<1536, 256, 0, stream>>>(xb, Wqb, Wkb, Wvb, tab, Q, K, VTg);

    dim3 g2(BB*HH, LL/128);
    attn_kernel<<<g2, 256, 0, stream>>>(Q, K, VTg, AOb);

    oproj_mfma_kernel<<<512, 256, 0, stream>>>(AOb, Wob, out);
}

// Round 8
// 249.384 us; speedup vs baseline: 1.2327x; 1.0186x over previous
//
#include <hip/hip_runtime.h>
#include <math.h>

#define BB 4
#define LL 2048
#define DD 1024
#define HH 16
#define HD 64
#define BL (BB*LL)

typedef __attribute__((ext_vector_type(8))) short bf16x8;
typedef __attribute__((ext_vector_type(4))) short bf16x4;
typedef __attribute__((ext_vector_type(4))) float f32x4;

__device__ inline short f2bf(float f) {
    union { float f; unsigned u; } v; v.f = f;
    unsigned r = v.u + 0x7fffu + ((v.u >> 16) & 1u);   // RNE
    return (short)(r >> 16);
}

// pack two fp32 -> two bf16 (truncation; p>=0 so bias is benign, ~2^-9 rel)
// single v_perm_b32: D = {b.b3, b.b2, a.b3, a.b2}
__device__ inline unsigned pk_bf16(float a, float b) {
    union { float f; unsigned u; } x, y; x.f = a; y.f = b;
#if __has_builtin(__builtin_amdgcn_perm)
    return __builtin_amdgcn_perm(y.u, x.u, 0x07060302u);
#else
    return (x.u >> 16) | (y.u & 0xffff0000u);
#endif
}

__device__ inline float exp2x(float x) {
#if __has_builtin(__builtin_amdgcn_exp2f)
    return __builtin_amdgcn_exp2f(x);
#else
    return exp2f(x);
#endif
}

__device__ inline void gload_lds16(const void* g, void* l) {
    __builtin_amdgcn_global_load_lds(
        (const __attribute__((address_space(1))) unsigned int*)g,
        (__attribute__((address_space(3))) unsigned int*)l, 16, 0, 0);
}

// ---------------------------------------------------------------------------
// Fused prep kernel — rope table + x cast + 4-weight cast in ONE launch.
// Block ranges: [0,4096) x-cast, [4096,6144) weight cast4, [6144,6400) rope.
// ---------------------------------------------------------------------------
#define NB_CASTX ((BL*DD)/2048)         // 4096
#define NB_CASTW (4*((DD*DD)/2048))     // 2048
#define NB_ROPE  256

__global__ __launch_bounds__(256) void prep_kernel(
    const float* __restrict__ x,
    const float* __restrict__ w0, const float* __restrict__ w1,
    const float* __restrict__ w2, const float* __restrict__ w3,
    short* __restrict__ xb, short* __restrict__ wout,
    float2* __restrict__ tab)
{
    const int bid = blockIdx.x;
    if (bid < NB_CASTX) {
        int i = (bid * 256 + threadIdx.x) * 8;
        float4 a = *(const float4*)(x + i);
        float4 b = *(const float4*)(x + i + 4);
        bf16x8 o;
        o[0]=f2bf(a.x); o[1]=f2bf(a.y); o[2]=f2bf(a.z); o[3]=f2bf(a.w);
        o[4]=f2bf(b.x); o[5]=f2bf(b.y); o[6]=f2bf(b.z); o[7]=f2bf(b.w);
        *(bf16x8*)(xb + i) = o;
    } else if (bid < NB_CASTX + NB_CASTW) {
        const int nw_blocks = (DD*DD) / 2048;    // 512
        int b2  = bid - NB_CASTX;
        int sel = b2 / nw_blocks;
        int blk = b2 % nw_blocks;
        const float* in = (sel == 0) ? w0 : (sel == 1) ? w1 : (sel == 2) ? w2 : w3;
        int i = (blk * 256 + threadIdx.x) * 8;
        float4 a = *(const float4*)(in + i);
        float4 b = *(const float4*)(in + i + 4);
        bf16x8 o;
        o[0]=f2bf(a.x); o[1]=f2bf(a.y); o[2]=f2bf(a.z); o[3]=f2bf(a.w);
        o[4]=f2bf(b.x); o[5]=f2bf(b.y); o[6]=f2bf(b.z); o[7]=f2bf(b.w);
        *(bf16x8*)(wout + (size_t)sel * DD * DD + i) = o;
    } else {
        int idx = (bid - NB_CASTX - NB_CASTW) * 256 + threadIdx.x;
        int lq = idx >> 5, f = idx & 31;
        float inv = __expf((float)f * (-9.210340371976184f / 32.0f));
        float s, c;
        sincosf((float)lq * inv, &s, &c);
        tab[idx] = make_float2(c, s);
    }
}

// ---------------------------------------------------------------------------
// Shared 128x128-tile bf16 MFMA K-loop (m97 2-barrier structure, 32 KB LDS).
// R11: XOR-swizzled LDS columns (rule #21: linear gload_lds dest +
// pre-swizzled GLOBAL source + swizzled read) — conflicts 1.9e7 -> 2.6e5.
// R12: callers pin __launch_bounds__(256,4) => VGPR cap 128 (132 crossed the
// 128 occupancy cliff: 19.6 -> 11%).
// ---------------------------------------------------------------------------
__device__ inline void gemm_bt_128(const short* __restrict__ A,
                                   const short* __restrict__ B,
                                   short* Ash, short* Bsh,
                                   int i0, int n0, f32x4 (&acc)[4][4])
{
    const int t  = threadIdx.x;
    const int w  = t >> 6;
    const int l  = t & 63;
    const int g  = (t >> 4) & 3;
    const int ln = t & 15;
    const int rh = (w >> 1) * 64;
    const int ch = (w & 1) * 64;
    const int srow = w * 8 + (l >> 3);
    const int skol = ((l & 7) ^ (l >> 3)) * 8;   // source col swizzled by row&7
    const int rsw  = 8 * (ln & 7);               // read-side XOR key (row&7 == ln&7)

    for (int k0 = 0; k0 < DD; k0 += 64) {
        __syncthreads();
        const short* ga = A + (size_t)(i0 + srow) * DD + k0 + skol;
        const short* gb = B + (size_t)(n0 + srow) * DD + k0 + skol;
        short* la = Ash + w * 512;   // wave-uniform base
        short* lb = Bsh + w * 512;
        #pragma unroll
        for (int j = 0; j < 4; ++j) {
            gload_lds16(ga + j * 32 * DD, la + j * 2048);
            gload_lds16(gb + j * 32 * DD, lb + j * 2048);
        }
        __syncthreads();

        #pragma unroll
        for (int kk = 0; kk < 2; ++kk) {
            bf16x8 af[4], bfr[4];
            #pragma unroll
            for (int mi = 0; mi < 4; ++mi)
                af[mi] = *(const bf16x8*)(Ash + (rh + mi*16 + ln)*64 + ((kk*32 + 8*g) ^ rsw));
            #pragma unroll
            for (int nj = 0; nj < 4; ++nj)
                bfr[nj] = *(const bf16x8*)(Bsh + (ch + nj*16 + ln)*64 + ((kk*32 + 8*g) ^ rsw));
            #pragma unroll
            for (int mi = 0; mi < 4; ++mi)
                #pragma unroll
                for (int nj = 0; nj < 4; ++nj)
                    acc[mi][nj] = __builtin_amdgcn_mfma_f32_16x16x32_bf16(
                        af[mi], bfr[nj], acc[mi][nj], 0, 0, 0);
        }
    }
}

// ---------------------------------------------------------------------------
// Kernel 1: QKV projection + RoPE. 1-D grid 1536, XCD-aware decode:
// xcd r = gid&7 owns i-tiles r*8..r*8+7 (2 MB of x stays in that XCD's L2)
// and iterates all 24 (n,z) W-tiles (W-tile reused back-to-back).
// z=0/1: Q/K roped via table, Q scaled 0.125*log2(e), layout (B,H,L,Hd).
// z=2: V transposed (B,H,Hd,L) via two-pass LDS transpose. V keys are
// bit-permuted within each 64-key tile (key' [5:4]=g,[3]=hb,[2]=a,[1:0]=r
// of key = 32hb+16a+4g+r) so attn's PV B-frags are single b128 LDS reads.
// ---------------------------------------------------------------------------
__global__ __launch_bounds__(256, 4) void qkv_mfma_kernel(
    const short* __restrict__ xb, const short* __restrict__ Wqb,
    const short* __restrict__ Wkb, const short* __restrict__ Wvb,
    const float2* __restrict__ rope_tab,
    short* __restrict__ Qo, short* __restrict__ Ko, short* __restrict__ Vo)
{
    __shared__ short Ash[128*64];
    __shared__ short Bsh[128*64];

    const int gid = blockIdx.x;
    const int r8  = gid & 7;           // XCD slot (round-robin heuristic)
    const int u   = gid >> 3;          // 0..191
    const int i_idx = r8 * 8 + (u & 7);      // 0..63
    const int nz  = u >> 3;                  // 0..23
    const int n_idx = nz & 7;                // 0..7
    const int z   = nz >> 3;                 // 0..2

    const short* Wm = (z == 0) ? Wqb : ((z == 1) ? Wkb : Wvb);
    const int i0 = i_idx * 128;
    const int n0 = n_idx * 128;

    f32x4 acc[4][4];
    #pragma unroll
    for (int mi = 0; mi < 4; ++mi)
        #pragma unroll
        for (int nj = 0; nj < 4; ++nj) acc[mi][nj] = (f32x4){0.f,0.f,0.f,0.f};

    gemm_bt_128(xb, Wm, Ash, Bsh, i0, n0, acc);

    const int t  = threadIdx.x;
    const int w  = t >> 6;
    const int g  = (t >> 4) & 3;
    const int ln = t & 15;
    const int rh = (w >> 1) * 64;

    if (z == 2) {
        // two passes over heads; buf[64 d][136 seq-stride] spans Ash..Bsh.
        short* buf = Ash;
        const int b = i0 >> 11, l0 = i0 & (LL - 1);
        const int d = t >> 2;
        const int c = t & 3;
        #pragma unroll
        for (int hp = 0; hp < 2; ++hp) {
            __syncthreads();
            if ((w & 1) == hp) {
                #pragma unroll
                for (int nj = 0; nj < 4; ++nj)
                    #pragma unroll
                    for (int mi = 0; mi < 4; ++mi)
                        #pragma unroll
                        for (int r = 0; r < 4; ++r)
                            buf[(nj*16 + ln)*136 + rh + mi*16 + 4*g + r]
                                = f2bf(acc[mi][nj][r]);
            }
            __syncthreads();
            short* dst = Vo + ((size_t)((b*HH + n_idx*2 + hp)*HD + d)) * LL + l0;
            // permuted store: global key base = 8c + 32j (within 128-row l0);
            // tile tb = 64*(j>>1), hb = j&1, a = c>>1, g0 = 2*(c&1);
            // keys k0..k0+3 -> key' 16*g0+8*hb+4*a..+3 ; k0+4..k0+7 -> g0+1.
            #pragma unroll
            for (int j = 0; j < 4; ++j) {
                const short* src = buf + d*136 + c*8 + j*32;
                bf16x4 lo = *(const bf16x4*)(src);
                bf16x4 hi = *(const bf16x4*)(src + 4);
                const int tb = (j >> 1) * 64;
                const int hb = j & 1;
                const int aa = c >> 1;
                const int g0 = (c & 1) * 2;
                *(bf16x4*)(dst + tb + g0*16       + hb*8 + aa*4) = lo;
                *(bf16x4*)(dst + tb + (g0+1)*16   + hb*8 + aa*4) = hi;
            }
        }
    } else {
        const int h = n_idx * 2 + (w & 1);
        short* Om = (z == 0) ? Qo : Ko;
        // Q: 1/sqrt(64) * log2(e) so scores feed exp2 directly
        const float sc = (z == 0) ? 0.180336880111112f : 1.0f;
        #pragma unroll
        for (int mi = 0; mi < 4; ++mi)
            #pragma unroll
            for (int r = 0; r < 4; ++r) {
                int i = i0 + rh + mi*16 + 4*g + r;
                int b = i >> 11, lq = i & (LL - 1);
                float2 cs0 = rope_tab[lq*32 + ln];        // freq ln
                float2 cs1 = rope_tab[lq*32 + ln + 16];   // freq ln+16
                float r0 = (acc[mi][0][r]*cs0.x - acc[mi][2][r]*cs0.y) * sc;
                float r2 = (acc[mi][2][r]*cs0.x + acc[mi][0][r]*cs0.y) * sc;
                float r1 = (acc[mi][1][r]*cs1.x - acc[mi][3][r]*cs1.y) * sc;
                float r3 = (acc[mi][3][r]*cs1.x + acc[mi][1][r]*cs1.y) * sc;
                size_t base = ((size_t)(b*HH + h) * LL + lq) * HD;
                Om[base + ln     ] = f2bf(r0);
                Om[base + ln + 16] = f2bf(r1);
                Om[base + ln + 32] = f2bf(r2);
                Om[base + ln + 48] = f2bf(r3);
            }
    }
}

// ---------------------------------------------------------------------------
// Kernel 2: bf16 MFMA flash attention (R12 form — R13's one-ahead prefetch
// reverted: +12 VGPR crossed the 64-reg occupancy cliff, 33->24.6%, and
// FETCH grew 24.7->38.6MB as K/V L2 co-residency degraded. At 60 VGPR there
// is no headroom for prefetch state; TLP > ILP here.)
// grid = (B*H, L/128): bh on x => the 16 q-tile blocks sharing one bh get
// gid == bh (mod 8) -> same XCD -> K/V stay in one L2.
//  (a) l-sum via MFMA ones-trick (lsum element r == O row 4g+r).
//  (b) VT global layout key-bit-permuted -> PV B-frag = one b128 LDS read.
//  (c) pk_bf16 = single v_perm_b32.
// ---------------------------------------------------------------------------
__global__ __launch_bounds__(256) void attn_kernel(
    const short* __restrict__ Q, const short* __restrict__ K,
    const short* __restrict__ VT, short* __restrict__ AO)
{
    __shared__ short Ksh[64*72];   // [key][d]
    __shared__ short VTs[64*72];   // [d][key']  (key' = permuted key)

    const int t  = threadIdx.x;
    const int w  = t >> 6;
    const int l  = t & 63;
    const int g  = l >> 4;
    const int ln = l & 15;

    const int bh = blockIdx.x;
    const int q0 = blockIdx.y * 128;
    const short* Qb  = Q  + ((size_t)bh * LL + q0 + w*32) * HD;
    const short* Kb  = K  + (size_t)bh * LL * HD;
    const short* VTb = VT + (size_t)bh * HD * LL;

    // Q B-frags: [n=q=ln][k=d=8g+j(+32)]
    bf16x8 qb[2][2];
    #pragma unroll
    for (int qi = 0; qi < 2; ++qi) {
        qb[qi][0] = *(const bf16x8*)(Qb + (size_t)(qi*16 + ln)*HD + 8*g);
        qb[qi][1] = *(const bf16x8*)(Qb + (size_t)(qi*16 + ln)*HD + 32 + 8*g);
    }

    const bf16x8 ONES = { (short)0x3F80, (short)0x3F80, (short)0x3F80, (short)0x3F80,
                          (short)0x3F80, (short)0x3F80, (short)0x3F80, (short)0x3F80 };

    f32x4 O[2][4];                 // O[qi][db]: row q=4g+r, col d=db*16+ln
    #pragma unroll
    for (int qi = 0; qi < 2; ++qi)
        #pragma unroll
        for (int db = 0; db < 4; ++db) O[qi][db] = (f32x4){0.f,0.f,0.f,0.f};
    f32x4 lsum[2];                 // lsum[qi][r] = l for row q=4g+r (any ln)
    lsum[0] = (f32x4){0.f,0.f,0.f,0.f};
    lsum[1] = (f32x4){0.f,0.f,0.f,0.f};

    const int sr = t >> 2;          // staging row (key for Ksh, d for VTs)
    const int sc = (t & 3) << 4;    // staging col chunk

    for (int kt = 0; kt < LL; kt += 64) {
        bf16x8 k0 = *(const bf16x8*)(Kb  + (size_t)(kt + sr)*HD + sc);
        bf16x8 k1 = *(const bf16x8*)(Kb  + (size_t)(kt + sr)*HD + sc + 8);
        bf16x8 v0 = *(const bf16x8*)(VTb + (size_t)sr*LL + kt + sc);
        bf16x8 v1 = *(const bf16x8*)(VTb + (size_t)sr*LL + kt + sc + 8);
        __syncthreads();           // previous tile fully consumed
        *(bf16x8*)(Ksh + sr*72 + sc)     = k0;
        *(bf16x8*)(Ksh + sr*72 + sc + 8) = k1;
        *(bf16x8*)(VTs + sr*72 + sc)     = v0;
        *(bf16x8*)(VTs + sr*72 + sc + 8) = v1;
        __syncthreads();

        unsigned pf[2][4][2];      // [qi][kb]: keys (4g,4g+1),(4g+2,4g+3)
        #pragma unroll
        for (int kb = 0; kb < 4; ++kb) {
            // K A-frags: [m=key=kb*16+ln][k=d]
            bf16x8 ka0 = *(const bf16x8*)(Ksh + (kb*16 + ln)*72 + 8*g);
            bf16x8 ka1 = *(const bf16x8*)(Ksh + (kb*16 + ln)*72 + 32 + 8*g);
            #pragma unroll
            for (int qi = 0; qi < 2; ++qi) {
                f32x4 S = (f32x4){0.f,0.f,0.f,0.f};
                S = __builtin_amdgcn_mfma_f32_16x16x32_bf16(ka0, qb[qi][0], S, 0, 0, 0);
                S = __builtin_amdgcn_mfma_f32_16x16x32_bf16(ka1, qb[qi][1], S, 0, 0, 0);
                float p0 = exp2x(S[0]), p1 = exp2x(S[1]);
                float p2 = exp2x(S[2]), p3 = exp2x(S[3]);
                pf[qi][kb][0] = pk_bf16(p0, p1);
                pf[qi][kb][1] = pk_bf16(p2, p3);
            }
        }

        // P A-frags for PV/lsum: slot (g,j) <-> key 32hb + 16*(j>>2) + 4g + (j&3)
        bf16x8 pa[2][2];
        #pragma unroll
        for (int qi = 0; qi < 2; ++qi)
            #pragma unroll
            for (int hb = 0; hb < 2; ++hb) {
                union { unsigned u[4]; bf16x8 v; } a;
                a.u[0] = pf[qi][2*hb][0];   a.u[1] = pf[qi][2*hb][1];
                a.u[2] = pf[qi][2*hb+1][0]; a.u[3] = pf[qi][2*hb+1][1];
                pa[qi][hb] = a.v;
            }

        // l-sum: one MFMA per (hb,qi) with all-ones B
        #pragma unroll
        for (int hb = 0; hb < 2; ++hb) {
            lsum[0] = __builtin_amdgcn_mfma_f32_16x16x32_bf16(pa[0][hb], ONES, lsum[0], 0, 0, 0);
            lsum[1] = __builtin_amdgcn_mfma_f32_16x16x32_bf16(pa[1][hb], ONES, lsum[1], 0, 0, 0);
        }

        // PV via 16x16x32: B-frag = one b128 from permuted VTs
        #pragma unroll
        for (int hb = 0; hb < 2; ++hb) {
            #pragma unroll
            for (int db = 0; db < 4; ++db) {
                bf16x8 vf = *(const bf16x8*)(VTs + (db*16 + ln)*72 + 16*g + 8*hb);
                O[0][db] = __builtin_amdgcn_mfma_f32_16x16x32_bf16(pa[0][hb], vf, O[0][db], 0, 0, 0);
                O[1][db] = __builtin_amdgcn_mfma_f32_16x16x32_bf16(pa[1][hb], vf, O[1][db], 0, 0, 0);
            }
        }
    }

    // epilogue: lsum[qi][r] is exactly l for row q=4g+r — no shuffles.
    const int b = bh >> 4, h = bh & 15;
    #pragma unroll
    for (int qi = 0; qi < 2; ++qi) {
        #pragma unroll
        for (int r = 0; r < 4; ++r) {
            float inv = 1.0f / lsum[qi][r];
            int q = q0 + w*32 + qi*16 + 4*g + r;
            size_t base = ((size_t)(b*LL + q)) * DD + h*HD;
            #pragma unroll
            for (int db = 0; db < 4; ++db)
                AO[base + db*16 + ln] = f2bf(O[qi][db][r] * inv);
        }
    }
}

// ---------------------------------------------------------------------------
// Kernel 3: output projection. 1-D grid 512, same XCD-aware decode as qkv:
// each XCD owns 8 i-tiles of A + iterates the 8 Wo n-tiles.
// ---------------------------------------------------------------------------
__global__ __launch_bounds__(256, 4) void oproj_mfma_kernel(
    const short* __restrict__ A, const short* __restrict__ Wob,
    float* __restrict__ out)
{
    __shared__ short Ash[128*64];
    __shared__ short Bsh[128*64];

    const int gid = blockIdx.x;
    const int r8  = gid & 7;
    const int u   = gid >> 3;              // 0..63
    const int i_idx = r8 * 8 + (u & 7);    // 0..63
    const int n_idx = u >> 3;              // 0..7
    const int i0 = i_idx * 128;
    const int n0 = n_idx * 128;

    f32x4 acc[4][4];
    #pragma unroll
    for (int mi = 0; mi < 4; ++mi)
        #pragma unroll
        for (int nj = 0; nj < 4; ++nj) acc[mi][nj] = (f32x4){0.f,0.f,0.f,0.f};

    gemm_bt_128(A, Wob, Ash, Bsh, i0, n0, acc);

    const int t  = threadIdx.x;
    const int w  = t >> 6;
    const int g  = (t >> 4) & 3;
    const int ln = t & 15;
    const int rh = (w >> 1) * 64;
    const int ch = (w & 1) * 64;

    #pragma unroll
    for (int mi = 0; mi < 4; ++mi)
        #pragma unroll
        for (int r = 0; r < 4; ++r) {
            size_t base = (size_t)(i0 + rh + mi*16 + 4*g + r) * DD + n0 + ch;
            #pragma unroll
            for (int nj = 0; nj < 4; ++nj)
                out[base + nj*16 + ln] = acc[mi][nj][r];
        }
}

// ---------------------------------------------------------------------------
extern "C" void kernel_launch(void* const* d_in, const int* in_sizes, int n_in,
                              void* d_out, int out_size, void* d_ws, size_t ws_size,
                              hipStream_t stream) {
    const float* x  = (const float*)d_in[0];
    const float* Wq = (const float*)d_in[1];
    const float* Wk = (const float*)d_in[2];
    const float* Wv = (const float*)d_in[3];
    const float* Wo = (const float*)d_in[4];
    float* out = (float*)d_out;

    const size_t n_x = (size_t)BL * DD;   // 8.4M
    const size_t n_w = (size_t)DD * DD;   // 1.05M
    short* xb  = (short*)d_ws;
    short* Wqb = xb  + n_x;               // Wqb..Wob contiguous (prep relies on it)
    short* Wkb = Wqb + n_w;
    short* Wvb = Wkb + n_w;
    short* Wob = Wvb + n_w;
    short* Q   = Wob + n_w;
    short* K   = Q   + n_x;
    short* VTg = K   + n_x;               // V transposed: (B,H,Hd,L), key-permuted
    short* AOb = VTg + n_x;
    float2* tab = (float2*)(AOb + n_x);   // 65536 float2 = 512 KB

    prep_kernel<<<NB_CASTX + NB_CASTW + NB_ROPE, 256, 0, stream>>>(
        x, Wq, Wk, Wv, Wo, xb, Wqb, tab);

    qkv_mfma_kernel<<<1536, 256, 0, stream>>>(xb, Wqb, Wkb, Wvb, tab, Q, K, VTg);

    dim3 g2(BB*HH, LL/128);
    attn_kernel<<<g2, 256, 0, stream>>>(Q, K, VTg, AOb);

    oproj_mfma_kernel<<<512, 256, 0, stream>>>(AOb, Wob, out);
}